// Round 6
// baseline (2623.069 us; speedup 1.0000x reference)
//
#include <hip/hip_runtime.h>
#include <hip/hip_bf16.h>
#include <cstdint>
#include <cstddef>

// BiLSTM tagger, f32 end-to-end.
// embed -> [GEMM pre -> 26x1-wave LSTM scan] x2 -> MLP GEMMs (dual) -> bilinear.
// Scan: 26 blocks (13 per direction), ONE 64-lane wave each,
// __attribute__((amdgpu_waves_per_eu(1,1))) -> 1 wave/SIMD -> ~512-VGPR budget, so
// the 200-VGPR weight array (one full 200-col Whh row per thread, 50 float4) stays
// register-resident (r3-r5: 8-wave blocks got capped at 68-128 VGPRs and the
// compiler REMATERIALIZED the weight loads into the loop -> L2-stream-bound).
// Thread = (gate = tid>>4, hidx = tid&15); block owns 16 h-indices (last block 8).
// Gate exchange via 4 in-wave __shfl (i,f,g,o at lanes hidx+{0,16,32,48}).
// Cross-block h exchange: packed (tag<<32|value) u64 words in L2, double-buffered
// by parity; reader batch-issues all 4 loads then tag-checks (one L2 RT).

#define TSEQ 512
#define HDIR 200
#define INSZ 400
#define G4   800

typedef unsigned long long u64;

// ---------------- embedding ----------------
__global__ void k_embed(const float* __restrict__ we, const float* __restrict__ pe,
                        const int* __restrict__ wi, const int* __restrict__ pi,
                        float* __restrict__ x) {
  int t = blockIdx.x;
  int w = wi[t], p = pi[t];
  const float* wrow = we + (size_t)w * 300;
  const float* prow = pe + (size_t)p * 100;
  for (int j = threadIdx.x; j < INSZ; j += blockDim.x)
    x[(size_t)t * INSZ + j] = (j < 300) ? wrow[j] : prow[j - 300];
}

__global__ void k_add(const float* __restrict__ a, const float* __restrict__ b,
                      float* __restrict__ o, int n) {
  int i = blockIdx.x * blockDim.x + threadIdx.x;
  if (i < n) o[i] = a[i] + b[i];
}

// ---------------- GEMM: C[n][m] = act(A[n][k] * B[m][k]^T + bias) ----------------
__device__ __forceinline__ void gemm_bt_body(
    const float* __restrict__ A, const float* __restrict__ B,
    const float* __restrict__ bias, float* __restrict__ C,
    int m, int k, int bias_mode, int do_relu, int bx, int by)
{
  __shared__ float As[16][68];
  __shared__ float Bs[16][68];
  const int tid = threadIdx.x;
  const int tx = tid & 15, ty = tid >> 4;
  const int row0 = by << 6, col0 = bx << 6;
  const int lr = tid >> 2;
  const int kq = (tid & 3) << 2;
  float acc[4][4] = {};

  for (int ks = 0; ks < k; ks += 16) {
    float4 a4 = *(const float4*)(A + (size_t)(row0 + lr) * k + ks + kq);
    float4 b4 = make_float4(0.f, 0.f, 0.f, 0.f);
    if (col0 + lr < m)
      b4 = *(const float4*)(B + (size_t)(col0 + lr) * k + ks + kq);
    As[kq + 0][lr] = a4.x; As[kq + 1][lr] = a4.y; As[kq + 2][lr] = a4.z; As[kq + 3][lr] = a4.w;
    Bs[kq + 0][lr] = b4.x; Bs[kq + 1][lr] = b4.y; Bs[kq + 2][lr] = b4.z; Bs[kq + 3][lr] = b4.w;
    __syncthreads();
#pragma unroll
    for (int kk = 0; kk < 16; ++kk) {
      const float4 av = *(const float4*)&As[kk][ty << 2];
      const float4 bv = *(const float4*)&Bs[kk][tx << 2];
      const float a_[4] = {av.x, av.y, av.z, av.w};
      const float b_[4] = {bv.x, bv.y, bv.z, bv.w};
#pragma unroll
      for (int i = 0; i < 4; ++i)
#pragma unroll
        for (int j = 0; j < 4; ++j)
          acc[i][j] += a_[i] * b_[j];
    }
    __syncthreads();
  }

#pragma unroll
  for (int i = 0; i < 4; ++i) {
    const int r = row0 + (ty << 2) + i;
#pragma unroll
    for (int j = 0; j < 4; ++j) {
      const int c = col0 + (tx << 2) + j;
      if (c < m) {
        float v = acc[i][j];
        if (bias_mode == 1) v += bias[c];
        else if (bias_mode == 2) v += bias[0];
        if (do_relu) v = fmaxf(v, 0.f);
        C[(size_t)r * m + c] = v;
      }
    }
  }
}

__global__ __launch_bounds__(256) void k_gemm_bt(
    const float* __restrict__ A, const float* __restrict__ B,
    const float* __restrict__ bias, float* __restrict__ C,
    int m, int k, int bias_mode, int do_relu)
{
  gemm_bt_body(A, B, bias, C, m, k, bias_mode, do_relu, blockIdx.x, blockIdx.y);
}

__global__ __launch_bounds__(256) void k_gemm_bt_dual(
    const float* __restrict__ A0, const float* __restrict__ B0,
    const float* __restrict__ bias0, float* __restrict__ C0,
    const float* __restrict__ A1, const float* __restrict__ B1,
    const float* __restrict__ bias1, float* __restrict__ C1,
    int m, int k, int bias_mode, int do_relu)
{
  const float* A = blockIdx.z ? A1 : A0;
  const float* B = blockIdx.z ? B1 : B0;
  const float* bias = blockIdx.z ? bias1 : bias0;
  float* C = blockIdx.z ? C1 : C0;
  gemm_bt_body(A, B, bias, C, m, k, bias_mode, do_relu, blockIdx.x, blockIdx.y);
}

// ---------------- LSTM scan ----------------
// grid = 26 x 64 threads. dir = bid&1, pb = bid>>1 (0..12), own h-indices
// [pb*16, pb*16+own_n), own_n = 16 (8 for pb==12). hbuf: u64[2 slot][2 dir][200].
__global__ __launch_bounds__(64) __attribute__((amdgpu_waves_per_eu(1, 1)))
void k_scan(const float* __restrict__ Whh,   // [2][2][800][200]
            const float* __restrict__ pre,   // [512][1600]
            float* __restrict__ hs,          // [512][400] (concat fwd|bwd)
            u64* hbuf,                       // zeroed by host each launch
            int layer)
{
  const int bid = blockIdx.x;
  const int dir = bid & 1;
  const int pb = bid >> 1;
  const int own0 = pb * 16;
  const int own_n = (own0 + 16 <= HDIR) ? 16 : (HDIR - own0);
  const int tid = threadIdx.x;
  const int gate = tid >> 4;          // 0..3 = i,f,g,o
  const int hloc = tid & 15;
  const bool act = hloc < own_n;
  const int grow = gate * HDIR + own0 + (act ? hloc : 0);

  __shared__ float h_lds[HDIR];

  float4 w[50];                        // one full Whh row, compile-time indices
  {
    const float* wrow = Whh + ((size_t)(layer * 2 + dir) * G4 + grow) * HDIR;
#pragma unroll
    for (int i = 0; i < 50; ++i) w[i] = *(const float4*)(wrow + i * 4);
  }

  for (int i = tid; i < HDIR; i += 64) h_lds[i] = 0.f;
  float c_state = 0.f;                 // valid for tid < own_n
  __syncthreads();

  for (int t = 0; t < TSEQ; ++t) {
    const int inrow = dir ? (TSEQ - 1 - t) : t;
    const float preval = act ? pre[(size_t)inrow * 1600 + dir * G4 + grow] : 0.f;

    if (t > 0) {       // gather full h_t: batch-issue 4 loads, then tag-check
      const u64* base = hbuf + (size_t)(t & 1) * 400 + dir * HDIR;
      u64 va = __hip_atomic_load(base + tid,       __ATOMIC_RELAXED, __HIP_MEMORY_SCOPE_AGENT);
      u64 vb = __hip_atomic_load(base + tid + 64,  __ATOMIC_RELAXED, __HIP_MEMORY_SCOPE_AGENT);
      u64 vc = __hip_atomic_load(base + tid + 128, __ATOMIC_RELAXED, __HIP_MEMORY_SCOPE_AGENT);
      u64 vd = (tid < 8) ? __hip_atomic_load(base + tid + 192, __ATOMIC_RELAXED, __HIP_MEMORY_SCOPE_AGENT)
                         : ((u64)0xFFFFFFFFu << 32);
      while ((unsigned)(va >> 32) < (unsigned)t)
        va = __hip_atomic_load(base + tid,       __ATOMIC_RELAXED, __HIP_MEMORY_SCOPE_AGENT);
      while ((unsigned)(vb >> 32) < (unsigned)t)
        vb = __hip_atomic_load(base + tid + 64,  __ATOMIC_RELAXED, __HIP_MEMORY_SCOPE_AGENT);
      while ((unsigned)(vc >> 32) < (unsigned)t)
        vc = __hip_atomic_load(base + tid + 128, __ATOMIC_RELAXED, __HIP_MEMORY_SCOPE_AGENT);
      while ((unsigned)(vd >> 32) < (unsigned)t)
        vd = __hip_atomic_load(base + tid + 192, __ATOMIC_RELAXED, __HIP_MEMORY_SCOPE_AGENT);
      union { unsigned uu; float f; } c0, c1, c2, c3;
      c0.uu = (unsigned)va; c1.uu = (unsigned)vb; c2.uu = (unsigned)vc; c3.uu = (unsigned)vd;
      h_lds[tid] = c0.f; h_lds[tid + 64] = c1.f; h_lds[tid + 128] = c2.f;
      if (tid < 8) h_lds[tid + 192] = c3.f;
    }
    __syncthreads();   // single wave: near-free; orders LDS writes vs reads

    // full-row FMA: gate pre-activation for (gate, own0+hloc)
    float4 a4 = make_float4(0.f, 0.f, 0.f, 0.f);
#pragma unroll
    for (int i = 0; i < 50; ++i) {
      const float4 hv = *(const float4*)(h_lds + i * 4);   // broadcast read
      a4.x += w[i].x * hv.x; a4.y += w[i].y * hv.y;
      a4.z += w[i].z * hv.z; a4.w += w[i].w * hv.w;
    }
    const float gv = a4.x + a4.y + a4.z + a4.w + preval;

    // activation: sigmoid for i,f,o; tanh for g (tanh = 2*sig(2x)-1)
    const float xx = (gate == 2) ? 2.f * gv : gv;
    const float s = 1.f / (1.f + __expf(-xx));
    const float av = (gate == 2) ? (2.f * s - 1.f) : s;

    // gate exchange within the wave
    const float ai = __shfl(av, hloc);
    const float af = __shfl(av, hloc + 16);
    const float ag = __shfl(av, hloc + 32);
    const float ao = __shfl(av, hloc + 48);

    if (tid < own_n) {                 // gate-0 lanes own the h update
      c_state = af * c_state + ai * ag;
      const float th = 2.f / (1.f + __expf(-2.f * c_state)) - 1.f;
      const float hv = ao * th;
      if (t != TSEQ - 1) {             // publish first: critical word leaves early
        union { float f; unsigned uu; } cv; cv.f = hv;
        const u64 pk = ((u64)(unsigned)(t + 1) << 32) | cv.uu;
        __hip_atomic_store(hbuf + (size_t)((t + 1) & 1) * 400 + dir * HDIR + own0 + tid,
                           pk, __ATOMIC_RELAXED, __HIP_MEMORY_SCOPE_AGENT);
      }
      hs[(size_t)inrow * INSZ + dir * HDIR + own0 + tid] = hv;
    }
  }
}

// ---------------- host ----------------
extern "C" void kernel_launch(void* const* d_in, const int* in_sizes, int n_in,
                              void* d_out, int out_size, void* d_ws, size_t ws_size,
                              hipStream_t stream)
{
  const float* we   = (const float*)d_in[0];
  const float* pe   = (const float*)d_in[1];
  const float* Wih  = (const float*)d_in[2];
  const float* Whh  = (const float*)d_in[3];
  const float* bih  = (const float*)d_in[4];
  const float* bhh  = (const float*)d_in[5];
  const float* W_h1 = (const float*)d_in[6];
  const float* b_h1 = (const float*)d_in[7];
  const float* W_h2 = (const float*)d_in[8];
  const float* b_h2 = (const float*)d_in[9];
  const float* W_d1 = (const float*)d_in[10];
  const float* b_d1 = (const float*)d_in[11];
  const float* W_d2 = (const float*)d_in[12];
  const float* b_d2 = (const float*)d_in[13];
  const float* W_bi = (const float*)d_in[14];
  const float* b_bi = (const float*)d_in[15];
  const int*   wi   = (const int*)d_in[16];
  const int*   pi   = (const int*)d_in[17];
  float* out = (float*)d_out;

  float* ws = (float*)d_ws;
  float* x0   = ws;                     // 512*400
  float* pre  = ws + 204800;            // 512*1600
  float* h1   = ws + 1024000;           // 512*400
  float* h2   = ws + 1228800;           // 512*400
  float* m1h  = ws + 1433600;           // 512*400
  float* m1d  = ws + 1638400;           // 512*400
  float* m2   = ws + 1843200;           // 512*400 (head)
  float* m3   = ws + 2048000;           // 512*400 (dep)
  float* t1   = ws + 2252800;           // 512*400
  float* bsum = ws + 2457600;           // 3200
  u64* hbuf0  = (u64*)(ws + 2461696);   // 800 u64, layer 0
  u64* hbuf1  = hbuf0 + 800;            // layer 1

  hipMemsetAsync(hbuf0, 0, 2 * 800 * sizeof(u64), stream);
  k_embed<<<TSEQ, 128, 0, stream>>>(we, pe, wi, pi, x0);
  k_add<<<(3200 + 255) / 256, 256, 0, stream>>>(bih, bhh, bsum, 3200);

  // layer 0
  k_gemm_bt<<<dim3(25, 8), 256, 0, stream>>>(x0, Wih, bsum, pre, 1600, 400, 1, 0);
  k_scan<<<26, 64, 0, stream>>>(Whh, pre, h1, hbuf0, 0);
  // layer 1
  k_gemm_bt<<<dim3(25, 8), 256, 0, stream>>>(h1, Wih + 1600 * 400, bsum + 1600, pre, 1600, 400, 1, 0);
  k_scan<<<26, 64, 0, stream>>>(Whh, pre, h2, hbuf1, 1);

  // head/dep stage 1 (dual), stage 2 (dual)
  k_gemm_bt_dual<<<dim3(7, 8, 2), 256, 0, stream>>>(h2, W_h1, b_h1, m1h,
                                                    h2, W_d1, b_d1, m1d, 400, 400, 1, 1);
  k_gemm_bt_dual<<<dim3(7, 8, 2), 256, 0, stream>>>(m1h, W_h2, b_h2, m2,
                                                    m1d, W_d2, b_d2, m3, 400, 400, 1, 1);

  // bilinear: t1[j][d] = sum_e dep[j][e] W_bi[d][e]; out[i][j] = head_i . t1_j + b
  k_gemm_bt<<<dim3(7, 8), 256, 0, stream>>>(m3, W_bi, nullptr, t1, 400, 400, 0, 0);
  k_gemm_bt<<<dim3(8, 8), 256, 0, stream>>>(m2, t1, b_bi, out, 512, 400, 2, 0);
}

// Round 7
// 2108.190 us; speedup vs baseline: 1.2442x; 1.2442x over previous
//
#include <hip/hip_runtime.h>
#include <hip/hip_bf16.h>
#include <cstdint>
#include <cstddef>

// BiLSTM tagger, f32 end-to-end.
// embed -> [GEMM pre -> 8-block LSTM scan] x2 -> MLP GEMMs (dual) -> bilinear.
// Scan: 8 working blocks (2 dirs x 4 parts), 448 thr. Each block: 200 gate rows,
// each row split across 2 threads (u = tid&1) -> 25 float4 = 100 weight VGPRs/thread.
// r3-r6 lesson: loop-invariant weight loads get REMATERIALIZED into the t-loop by
// the register allocator (VGPR_Count stuck at 68-132 regardless of launch bounds /
// waves_per_eu). Fix: pin w[] via empty inline-asm "+v" defs (not rematerializable)
// + amdgpu_waves_per_eu(1,2) so the 256-VGPR budget accommodates ~130 live regs.
// Cross-block h exchange: packed (tag<<32|value) u64 words in L2, double-buffered
// by parity; reader spins on the data word itself.

#define TSEQ 512
#define HDIR 200
#define INSZ 400
#define G4   800

typedef unsigned long long u64;

// ---------------- embedding ----------------
__global__ void k_embed(const float* __restrict__ we, const float* __restrict__ pe,
                        const int* __restrict__ wi, const int* __restrict__ pi,
                        float* __restrict__ x) {
  int t = blockIdx.x;
  int w = wi[t], p = pi[t];
  const float* wrow = we + (size_t)w * 300;
  const float* prow = pe + (size_t)p * 100;
  for (int j = threadIdx.x; j < INSZ; j += blockDim.x)
    x[(size_t)t * INSZ + j] = (j < 300) ? wrow[j] : prow[j - 300];
}

__global__ void k_add(const float* __restrict__ a, const float* __restrict__ b,
                      float* __restrict__ o, int n) {
  int i = blockIdx.x * blockDim.x + threadIdx.x;
  if (i < n) o[i] = a[i] + b[i];
}

// ---------------- GEMM: C[n][m] = act(A[n][k] * B[m][k]^T + bias) ----------------
__device__ __forceinline__ void gemm_bt_body(
    const float* __restrict__ A, const float* __restrict__ B,
    const float* __restrict__ bias, float* __restrict__ C,
    int m, int k, int bias_mode, int do_relu, int bx, int by)
{
  __shared__ float As[16][68];
  __shared__ float Bs[16][68];
  const int tid = threadIdx.x;
  const int tx = tid & 15, ty = tid >> 4;
  const int row0 = by << 6, col0 = bx << 6;
  const int lr = tid >> 2;
  const int kq = (tid & 3) << 2;
  float acc[4][4] = {};

  for (int ks = 0; ks < k; ks += 16) {
    float4 a4 = *(const float4*)(A + (size_t)(row0 + lr) * k + ks + kq);
    float4 b4 = make_float4(0.f, 0.f, 0.f, 0.f);
    if (col0 + lr < m)
      b4 = *(const float4*)(B + (size_t)(col0 + lr) * k + ks + kq);
    As[kq + 0][lr] = a4.x; As[kq + 1][lr] = a4.y; As[kq + 2][lr] = a4.z; As[kq + 3][lr] = a4.w;
    Bs[kq + 0][lr] = b4.x; Bs[kq + 1][lr] = b4.y; Bs[kq + 2][lr] = b4.z; Bs[kq + 3][lr] = b4.w;
    __syncthreads();
#pragma unroll
    for (int kk = 0; kk < 16; ++kk) {
      const float4 av = *(const float4*)&As[kk][ty << 2];
      const float4 bv = *(const float4*)&Bs[kk][tx << 2];
      const float a_[4] = {av.x, av.y, av.z, av.w};
      const float b_[4] = {bv.x, bv.y, bv.z, bv.w};
#pragma unroll
      for (int i = 0; i < 4; ++i)
#pragma unroll
        for (int j = 0; j < 4; ++j)
          acc[i][j] += a_[i] * b_[j];
    }
    __syncthreads();
  }

#pragma unroll
  for (int i = 0; i < 4; ++i) {
    const int r = row0 + (ty << 2) + i;
#pragma unroll
    for (int j = 0; j < 4; ++j) {
      const int c = col0 + (tx << 2) + j;
      if (c < m) {
        float v = acc[i][j];
        if (bias_mode == 1) v += bias[c];
        else if (bias_mode == 2) v += bias[0];
        if (do_relu) v = fmaxf(v, 0.f);
        C[(size_t)r * m + c] = v;
      }
    }
  }
}

__global__ __launch_bounds__(256) void k_gemm_bt(
    const float* __restrict__ A, const float* __restrict__ B,
    const float* __restrict__ bias, float* __restrict__ C,
    int m, int k, int bias_mode, int do_relu)
{
  gemm_bt_body(A, B, bias, C, m, k, bias_mode, do_relu, blockIdx.x, blockIdx.y);
}

__global__ __launch_bounds__(256) void k_gemm_bt_dual(
    const float* __restrict__ A0, const float* __restrict__ B0,
    const float* __restrict__ bias0, float* __restrict__ C0,
    const float* __restrict__ A1, const float* __restrict__ B1,
    const float* __restrict__ bias1, float* __restrict__ C1,
    int m, int k, int bias_mode, int do_relu)
{
  const float* A = blockIdx.z ? A1 : A0;
  const float* B = blockIdx.z ? B1 : B0;
  const float* bias = blockIdx.z ? bias1 : bias0;
  float* C = blockIdx.z ? C1 : C0;
  gemm_bt_body(A, B, bias, C, m, k, bias_mode, do_relu, blockIdx.x, blockIdx.y);
}

// ---------------- LSTM scan ----------------
// Working blocks: dir = bid&7 (0/1), part p = bid>>3 (0..3); others exit.
// Thread (rr = tid>>1, u = tid&1), rr<200: gate g = rr/50, q = rr%50,
// grow = g*200 + p*50 + q; columns [u*100, u*100+100) -> 25 float4 VGPRs.
// Block owns h slice [p*50, (p+1)*50). hbuf: u64[2 slot][2 dir][200].
__global__ __launch_bounds__(448, 1) __attribute__((amdgpu_waves_per_eu(1, 2)))
void k_scan(const float* __restrict__ Whh,   // [2][2][800][200]
            const float* __restrict__ pre,   // [512][1600]
            float* __restrict__ hs,          // [512][400] (concat fwd|bwd)
            u64* hbuf,                       // zeroed by host each launch
            int layer)
{
  const int bid = blockIdx.x;
  if ((bid & 7) > 1) return;
  const int dir = bid & 7;
  const int p = bid >> 3;
  const int tid = threadIdx.x;
  const int rr = tid >> 1;
  const int u = tid & 1;
  const bool act = rr < HDIR;
  const int g = rr / 50;
  const int q = rr - g * 50;
  const int grow = act ? (g * HDIR + p * 50 + q) : 0;
  const int own0 = p * 50;

  __shared__ float h_lds[HDIR];
  __shared__ float g_lds[HDIR];      // activated gate values [g*50+q]

  float4 w[25];                      // compile-time indices only
  {
    const float* wrow = Whh + ((size_t)(layer * 2 + dir) * G4 + grow) * HDIR + u * 100;
#pragma unroll
    for (int i = 0; i < 25; ++i) w[i] = *(const float4*)(wrow + i * 4);
  }
  // Pin weights in VGPRs: make each component's def an inline asm (NOT a
  // rematerializable invariant load). r3-r6: without this the allocator
  // re-issues the 25 dwordx4 loads from L2 inside every t-iteration.
#pragma unroll
  for (int i = 0; i < 25; ++i)
    asm volatile("" : "+v"(w[i].x), "+v"(w[i].y), "+v"(w[i].z), "+v"(w[i].w));

  for (int i = tid; i < HDIR; i += 448) h_lds[i] = 0.f;
  float c_state = 0.f;               // valid for tid < 50
  u64* hb_dir = hbuf + dir * HDIR;   // + slot*400
  __syncthreads();

  for (int t = 0; t < TSEQ; ++t) {
    const int inrow = dir ? (TSEQ - 1 - t) : t;

    float preval = 0.f;
    if (act && u == 0)
      preval = pre[(size_t)inrow * 1600 + dir * G4 + grow];

    // gather 3 remote 50-slices (packed words; tag carries the data)
    if (t > 0 && tid < 150) {
      const int j = (tid < own0) ? tid : tid + 50;
      const u64* src = hb_dir + (size_t)(t & 1) * 400 + j;
      u64 v;
      do {
        v = __hip_atomic_load(src, __ATOMIC_RELAXED, __HIP_MEMORY_SCOPE_AGENT);
      } while ((unsigned)(v >> 32) < (unsigned)t);
      union { unsigned uu; float f; } cv; cv.uu = (unsigned)v;
      h_lds[j] = cv.f;
    }
    __syncthreads();   // B1: h_lds complete (own written end of prev iter)

    if (act) {
      float4 acc = make_float4(0.f, 0.f, 0.f, 0.f);
      const float* hb = h_lds + u * 100;
#pragma unroll
      for (int i = 0; i < 25; ++i) {
        const float4 hv = *(const float4*)(hb + i * 4);
        acc.x += w[i].x * hv.x; acc.y += w[i].y * hv.y;
        acc.z += w[i].z * hv.z; acc.w += w[i].w * hv.w;
      }
      float tot = acc.x + acc.y + acc.z + acc.w;
      tot += __shfl_xor(tot, 1);     // combine column halves (adjacent lanes)
      if (u == 0) {
        const float gv = tot + preval;
        const float xx = (g == 2) ? 2.f * gv : gv;     // tanh = 2*sig(2x)-1
        const float s = 1.f / (1.f + __expf(-xx));
        g_lds[rr] = (g == 2) ? (2.f * s - 1.f) : s;
      }
    }
    __syncthreads();   // B2: g_lds ready

    if (tid < 50) {
      const float ai = g_lds[tid];
      const float af = g_lds[50 + tid];
      const float ag = g_lds[100 + tid];
      const float ao = g_lds[150 + tid];
      c_state = af * c_state + ai * ag;
      const float th = 2.f / (1.f + __expf(-2.f * c_state)) - 1.f;
      const float hv = ao * th;
      if (t != TSEQ - 1) {           // publish first: critical L2 word leaves early
        union { float f; unsigned uu; } cv; cv.f = hv;
        const u64 pk = ((u64)(unsigned)(t + 1) << 32) | cv.uu;
        __hip_atomic_store(hb_dir + (size_t)((t + 1) & 1) * 400 + own0 + tid,
                           pk, __ATOMIC_RELAXED, __HIP_MEMORY_SCOPE_AGENT);
      }
      h_lds[own0 + tid] = hv;
      hs[(size_t)inrow * INSZ + dir * HDIR + own0 + tid] = hv;
    }
    // no barrier here: B1 of next iter orders h_lds[own] for FMA readers;
    // spin writers touch disjoint h_lds slices after passing B2.
  }
}

// ---------------- host ----------------
extern "C" void kernel_launch(void* const* d_in, const int* in_sizes, int n_in,
                              void* d_out, int out_size, void* d_ws, size_t ws_size,
                              hipStream_t stream)
{
  const float* we   = (const float*)d_in[0];
  const float* pe   = (const float*)d_in[1];
  const float* Wih  = (const float*)d_in[2];
  const float* Whh  = (const float*)d_in[3];
  const float* bih  = (const float*)d_in[4];
  const float* bhh  = (const float*)d_in[5];
  const float* W_h1 = (const float*)d_in[6];
  const float* b_h1 = (const float*)d_in[7];
  const float* W_h2 = (const float*)d_in[8];
  const float* b_h2 = (const float*)d_in[9];
  const float* W_d1 = (const float*)d_in[10];
  const float* b_d1 = (const float*)d_in[11];
  const float* W_d2 = (const float*)d_in[12];
  const float* b_d2 = (const float*)d_in[13];
  const float* W_bi = (const float*)d_in[14];
  const float* b_bi = (const float*)d_in[15];
  const int*   wi   = (const int*)d_in[16];
  const int*   pi   = (const int*)d_in[17];
  float* out = (float*)d_out;

  float* ws = (float*)d_ws;
  float* x0   = ws;                     // 512*400
  float* pre  = ws + 204800;            // 512*1600
  float* h1   = ws + 1024000;           // 512*400
  float* h2   = ws + 1228800;           // 512*400
  float* m1h  = ws + 1433600;           // 512*400
  float* m1d  = ws + 1638400;           // 512*400
  float* m2   = ws + 1843200;           // 512*400 (head)
  float* m3   = ws + 2048000;           // 512*400 (dep)
  float* t1   = ws + 2252800;           // 512*400
  float* bsum = ws + 2457600;           // 3200
  u64* hbuf0  = (u64*)(ws + 2461696);   // 800 u64, layer 0
  u64* hbuf1  = hbuf0 + 800;            // layer 1

  hipMemsetAsync(hbuf0, 0, 2 * 800 * sizeof(u64), stream);
  k_embed<<<TSEQ, 128, 0, stream>>>(we, pe, wi, pi, x0);
  k_add<<<(3200 + 255) / 256, 256, 0, stream>>>(bih, bhh, bsum, 3200);

  // layer 0
  k_gemm_bt<<<dim3(25, 8), 256, 0, stream>>>(x0, Wih, bsum, pre, 1600, 400, 1, 0);
  k_scan<<<26, 448, 0, stream>>>(Whh, pre, h1, hbuf0, 0);
  // layer 1
  k_gemm_bt<<<dim3(25, 8), 256, 0, stream>>>(h1, Wih + 1600 * 400, bsum + 1600, pre, 1600, 400, 1, 0);
  k_scan<<<26, 448, 0, stream>>>(Whh, pre, h2, hbuf1, 1);

  // head/dep stage 1 (dual), stage 2 (dual)
  k_gemm_bt_dual<<<dim3(7, 8, 2), 256, 0, stream>>>(h2, W_h1, b_h1, m1h,
                                                    h2, W_d1, b_d1, m1d, 400, 400, 1, 1);
  k_gemm_bt_dual<<<dim3(7, 8, 2), 256, 0, stream>>>(m1h, W_h2, b_h2, m2,
                                                    m1d, W_d2, b_d2, m3, 400, 400, 1, 1);

  // bilinear: t1[j][d] = sum_e dep[j][e] W_bi[d][e]; out[i][j] = head_i . t1_j + b
  k_gemm_bt<<<dim3(7, 8), 256, 0, stream>>>(m3, W_bi, nullptr, t1, 400, 400, 0, 0);
  k_gemm_bt<<<dim3(8, 8), 256, 0, stream>>>(m2, t1, b_bi, out, 512, 400, 2, 0);
}

// Round 8
// 2014.317 us; speedup vs baseline: 1.3022x; 1.0466x over previous
//
#include <hip/hip_runtime.h>
#include <hip/hip_bf16.h>
#include <cstdint>
#include <cstddef>

// BiLSTM tagger, f32 end-to-end.
// embed -> [GEMM pre -> 8-block LSTM scan] x2 -> MLP GEMMs (dual) -> bilinear.
// Scan: 8 working blocks (2 dirs x 4 parts), 448 thr; 25 float4 = 100 weight
// VGPRs/thread. The r3-r7 saga: the register allocator either REMATERIALIZES
// loop-invariant weight loads into the t-loop (r5: budget 68, r6: budget 132)
// or SPILLS pinned values (r7: launch_bounds(448,1)+waves_per_eu(1,2) collapsed
// the budget to 64). Fix needs BOTH: (a) remat-proof defs via empty inline-asm
// "+v" (r7), and (b) a big budget via waves_per_eu(1,1) with NO conflicting
// __launch_bounds__ (r6 showed 1,1 alone lifts the cap: VGPR 132).
// Cross-block h exchange: packed (tag<<32|value) u64 words in L2, double-buffered
// by parity; reader spins on the data word itself.

#define TSEQ 512
#define HDIR 200
#define INSZ 400
#define G4   800

typedef unsigned long long u64;

// ---------------- embedding ----------------
__global__ void k_embed(const float* __restrict__ we, const float* __restrict__ pe,
                        const int* __restrict__ wi, const int* __restrict__ pi,
                        float* __restrict__ x) {
  int t = blockIdx.x;
  int w = wi[t], p = pi[t];
  const float* wrow = we + (size_t)w * 300;
  const float* prow = pe + (size_t)p * 100;
  for (int j = threadIdx.x; j < INSZ; j += blockDim.x)
    x[(size_t)t * INSZ + j] = (j < 300) ? wrow[j] : prow[j - 300];
}

__global__ void k_add(const float* __restrict__ a, const float* __restrict__ b,
                      float* __restrict__ o, int n) {
  int i = blockIdx.x * blockDim.x + threadIdx.x;
  if (i < n) o[i] = a[i] + b[i];
}

// ---------------- GEMM: C[n][m] = act(A[n][k] * B[m][k]^T + bias) ----------------
__device__ __forceinline__ void gemm_bt_body(
    const float* __restrict__ A, const float* __restrict__ B,
    const float* __restrict__ bias, float* __restrict__ C,
    int m, int k, int bias_mode, int do_relu, int bx, int by)
{
  __shared__ float As[16][68];
  __shared__ float Bs[16][68];
  const int tid = threadIdx.x;
  const int tx = tid & 15, ty = tid >> 4;
  const int row0 = by << 6, col0 = bx << 6;
  const int lr = tid >> 2;
  const int kq = (tid & 3) << 2;
  float acc[4][4] = {};

  for (int ks = 0; ks < k; ks += 16) {
    float4 a4 = *(const float4*)(A + (size_t)(row0 + lr) * k + ks + kq);
    float4 b4 = make_float4(0.f, 0.f, 0.f, 0.f);
    if (col0 + lr < m)
      b4 = *(const float4*)(B + (size_t)(col0 + lr) * k + ks + kq);
    As[kq + 0][lr] = a4.x; As[kq + 1][lr] = a4.y; As[kq + 2][lr] = a4.z; As[kq + 3][lr] = a4.w;
    Bs[kq + 0][lr] = b4.x; Bs[kq + 1][lr] = b4.y; Bs[kq + 2][lr] = b4.z; Bs[kq + 3][lr] = b4.w;
    __syncthreads();
#pragma unroll
    for (int kk = 0; kk < 16; ++kk) {
      const float4 av = *(const float4*)&As[kk][ty << 2];
      const float4 bv = *(const float4*)&Bs[kk][tx << 2];
      const float a_[4] = {av.x, av.y, av.z, av.w};
      const float b_[4] = {bv.x, bv.y, bv.z, bv.w};
#pragma unroll
      for (int i = 0; i < 4; ++i)
#pragma unroll
        for (int j = 0; j < 4; ++j)
          acc[i][j] += a_[i] * b_[j];
    }
    __syncthreads();
  }

#pragma unroll
  for (int i = 0; i < 4; ++i) {
    const int r = row0 + (ty << 2) + i;
#pragma unroll
    for (int j = 0; j < 4; ++j) {
      const int c = col0 + (tx << 2) + j;
      if (c < m) {
        float v = acc[i][j];
        if (bias_mode == 1) v += bias[c];
        else if (bias_mode == 2) v += bias[0];
        if (do_relu) v = fmaxf(v, 0.f);
        C[(size_t)r * m + c] = v;
      }
    }
  }
}

__global__ __launch_bounds__(256) void k_gemm_bt(
    const float* __restrict__ A, const float* __restrict__ B,
    const float* __restrict__ bias, float* __restrict__ C,
    int m, int k, int bias_mode, int do_relu)
{
  gemm_bt_body(A, B, bias, C, m, k, bias_mode, do_relu, blockIdx.x, blockIdx.y);
}

__global__ __launch_bounds__(256) void k_gemm_bt_dual(
    const float* __restrict__ A0, const float* __restrict__ B0,
    const float* __restrict__ bias0, float* __restrict__ C0,
    const float* __restrict__ A1, const float* __restrict__ B1,
    const float* __restrict__ bias1, float* __restrict__ C1,
    int m, int k, int bias_mode, int do_relu)
{
  const float* A = blockIdx.z ? A1 : A0;
  const float* B = blockIdx.z ? B1 : B0;
  const float* bias = blockIdx.z ? bias1 : bias0;
  float* C = blockIdx.z ? C1 : C0;
  gemm_bt_body(A, B, bias, C, m, k, bias_mode, do_relu, blockIdx.x, blockIdx.y);
}

// ---------------- LSTM scan ----------------
// Working blocks: dir = bid&7 (0/1), part p = bid>>3 (0..3); others exit.
// Thread (rr = tid>>1, u = tid&1), rr<200: gate g = rr/50, q = rr%50,
// grow = g*200 + p*50 + q; columns [u*100, u*100+100) -> 25 float4 VGPRs.
// Block owns h slice [p*50, (p+1)*50). hbuf: u64[2 slot][2 dir][200].
__global__ __attribute__((amdgpu_flat_work_group_size(448, 448)))
__attribute__((amdgpu_waves_per_eu(1, 1)))
void k_scan(const float* __restrict__ Whh,   // [2][2][800][200]
            const float* __restrict__ pre,   // [512][1600]
            float* __restrict__ hs,          // [512][400] (concat fwd|bwd)
            u64* hbuf,                       // zeroed by host each launch
            int layer)
{
  const int bid = blockIdx.x;
  if ((bid & 7) > 1) return;
  const int dir = bid & 7;
  const int p = bid >> 3;
  const int tid = threadIdx.x;
  const int rr = tid >> 1;
  const int u = tid & 1;
  const bool act = rr < HDIR;
  const int g = rr / 50;
  const int q = rr - g * 50;
  const int grow = act ? (g * HDIR + p * 50 + q) : 0;
  const int own0 = p * 50;

  __shared__ float h_lds[HDIR];
  __shared__ float g_lds[HDIR];      // activated gate values [g*50+q]

  float4 w[25];                      // compile-time indices only
  {
    const float* wrow = Whh + ((size_t)(layer * 2 + dir) * G4 + grow) * HDIR + u * 100;
#pragma unroll
    for (int i = 0; i < 25; ++i) w[i] = *(const float4*)(wrow + i * 4);
  }
  // Pin: make each component's def an inline asm (not a rematerializable load).
  // With waves_per_eu(1,1)'s 512-VGPR budget the allocator keeps them live.
#pragma unroll
  for (int i = 0; i < 25; ++i)
    asm volatile("" : "+v"(w[i].x), "+v"(w[i].y), "+v"(w[i].z), "+v"(w[i].w));

  for (int i = tid; i < HDIR; i += 448) h_lds[i] = 0.f;
  float c_state = 0.f;               // valid for tid < 50
  u64* hb_dir = hbuf + dir * HDIR;   // + slot*400
  __syncthreads();

  for (int t = 0; t < TSEQ; ++t) {
    const int inrow = dir ? (TSEQ - 1 - t) : t;

    float preval = 0.f;
    if (act && u == 0)
      preval = pre[(size_t)inrow * 1600 + dir * G4 + grow];

    // gather 3 remote 50-slices (packed words; tag carries the data)
    if (t > 0 && tid < 150) {
      const int j = (tid < own0) ? tid : tid + 50;
      const u64* src = hb_dir + (size_t)(t & 1) * 400 + j;
      u64 v;
      do {
        v = __hip_atomic_load(src, __ATOMIC_RELAXED, __HIP_MEMORY_SCOPE_AGENT);
      } while ((unsigned)(v >> 32) < (unsigned)t);
      union { unsigned uu; float f; } cv; cv.uu = (unsigned)v;
      h_lds[j] = cv.f;
    }
    __syncthreads();   // B1: h_lds complete (own written end of prev iter)

    if (act) {
      float4 acc = make_float4(0.f, 0.f, 0.f, 0.f);
      const float* hb = h_lds + u * 100;
#pragma unroll
      for (int i = 0; i < 25; ++i) {
        const float4 hv = *(const float4*)(hb + i * 4);
        acc.x += w[i].x * hv.x; acc.y += w[i].y * hv.y;
        acc.z += w[i].z * hv.z; acc.w += w[i].w * hv.w;
      }
      float tot = acc.x + acc.y + acc.z + acc.w;
      tot += __shfl_xor(tot, 1);     // combine column halves (adjacent lanes)
      if (u == 0) {
        const float gv = tot + preval;
        const float xx = (g == 2) ? 2.f * gv : gv;     // tanh = 2*sig(2x)-1
        const float s = 1.f / (1.f + __expf(-xx));
        g_lds[rr] = (g == 2) ? (2.f * s - 1.f) : s;
      }
    }
    __syncthreads();   // B2: g_lds ready

    if (tid < 50) {
      const float ai = g_lds[tid];
      const float af = g_lds[50 + tid];
      const float ag = g_lds[100 + tid];
      const float ao = g_lds[150 + tid];
      c_state = af * c_state + ai * ag;
      const float th = 2.f / (1.f + __expf(-2.f * c_state)) - 1.f;
      const float hv = ao * th;
      if (t != TSEQ - 1) {           // publish first: critical L2 word leaves early
        union { float f; unsigned uu; } cv; cv.f = hv;
        const u64 pk = ((u64)(unsigned)(t + 1) << 32) | cv.uu;
        __hip_atomic_store(hb_dir + (size_t)((t + 1) & 1) * 400 + own0 + tid,
                           pk, __ATOMIC_RELAXED, __HIP_MEMORY_SCOPE_AGENT);
      }
      h_lds[own0 + tid] = hv;
      hs[(size_t)inrow * INSZ + dir * HDIR + own0 + tid] = hv;
    }
    // no barrier here: B1 of next iter orders h_lds[own] for FMA readers;
    // spin writers touch disjoint h_lds slices after passing B2.
  }
}

// ---------------- host ----------------
extern "C" void kernel_launch(void* const* d_in, const int* in_sizes, int n_in,
                              void* d_out, int out_size, void* d_ws, size_t ws_size,
                              hipStream_t stream)
{
  const float* we   = (const float*)d_in[0];
  const float* pe   = (const float*)d_in[1];
  const float* Wih  = (const float*)d_in[2];
  const float* Whh  = (const float*)d_in[3];
  const float* bih  = (const float*)d_in[4];
  const float* bhh  = (const float*)d_in[5];
  const float* W_h1 = (const float*)d_in[6];
  const float* b_h1 = (const float*)d_in[7];
  const float* W_h2 = (const float*)d_in[8];
  const float* b_h2 = (const float*)d_in[9];
  const float* W_d1 = (const float*)d_in[10];
  const float* b_d1 = (const float*)d_in[11];
  const float* W_d2 = (const float*)d_in[12];
  const float* b_d2 = (const float*)d_in[13];
  const float* W_bi = (const float*)d_in[14];
  const float* b_bi = (const float*)d_in[15];
  const int*   wi   = (const int*)d_in[16];
  const int*   pi   = (const int*)d_in[17];
  float* out = (float*)d_out;

  float* ws = (float*)d_ws;
  float* x0   = ws;                     // 512*400
  float* pre  = ws + 204800;            // 512*1600
  float* h1   = ws + 1024000;           // 512*400
  float* h2   = ws + 1228800;           // 512*400
  float* m1h  = ws + 1433600;           // 512*400
  float* m1d  = ws + 1638400;           // 512*400
  float* m2   = ws + 1843200;           // 512*400 (head)
  float* m3   = ws + 2048000;           // 512*400 (dep)
  float* t1   = ws + 2252800;           // 512*400
  float* bsum = ws + 2457600;           // 3200
  u64* hbuf0  = (u64*)(ws + 2461696);   // 800 u64, layer 0
  u64* hbuf1  = hbuf0 + 800;            // layer 1

  hipMemsetAsync(hbuf0, 0, 2 * 800 * sizeof(u64), stream);
  k_embed<<<TSEQ, 128, 0, stream>>>(we, pe, wi, pi, x0);
  k_add<<<(3200 + 255) / 256, 256, 0, stream>>>(bih, bhh, bsum, 3200);

  // layer 0
  k_gemm_bt<<<dim3(25, 8), 256, 0, stream>>>(x0, Wih, bsum, pre, 1600, 400, 1, 0);
  k_scan<<<26, 448, 0, stream>>>(Whh, pre, h1, hbuf0, 0);
  // layer 1
  k_gemm_bt<<<dim3(25, 8), 256, 0, stream>>>(h1, Wih + 1600 * 400, bsum + 1600, pre, 1600, 400, 1, 0);
  k_scan<<<26, 448, 0, stream>>>(Whh, pre, h2, hbuf1, 1);

  // head/dep stage 1 (dual), stage 2 (dual)
  k_gemm_bt_dual<<<dim3(7, 8, 2), 256, 0, stream>>>(h2, W_h1, b_h1, m1h,
                                                    h2, W_d1, b_d1, m1d, 400, 400, 1, 1);
  k_gemm_bt_dual<<<dim3(7, 8, 2), 256, 0, stream>>>(m1h, W_h2, b_h2, m2,
                                                    m1d, W_d2, b_d2, m3, 400, 400, 1, 1);

  // bilinear: t1[j][d] = sum_e dep[j][e] W_bi[d][e]; out[i][j] = head_i . t1_j + b
  k_gemm_bt<<<dim3(7, 8), 256, 0, stream>>>(m3, W_bi, nullptr, t1, 400, 400, 0, 0);
  k_gemm_bt<<<dim3(8, 8), 256, 0, stream>>>(m2, t1, b_bi, out, 512, 400, 2, 0);
}